// Round 2
// baseline (138.476 us; speedup 1.0000x reference)
//
#include <hip/hip_runtime.h>
#include <hip/hip_bf16.h>

// BilinearPooling: out[i,k] = mean_j(conv1[i,j]) * conv2[i,k]
// B=256, J=K=14*14*256=50176.
//
// R1 analysis: single fused kernel at grid=256 was latency-bound
// (1 block/CU, 33% occupancy, 2.3 TB/s). Split into two kernels with
// 4096 blocks each (16 segments/row) for full wave parallelism.

#define NROWS     256
#define ROW_ELEMS 50176          // 14*14*256
#define ROW_VEC   (ROW_ELEMS/4)  // 12544 float4 per row
#define SEGS      16
#define SEG_VEC   (ROW_VEC/SEGS) // 784 float4 per segment
#define THREADS   256

// Kernel A: per-(row,segment) partial sums of conv1 -> partials[row*SEGS+seg]
__global__ __launch_bounds__(THREADS)
void bp_reduce_kernel(const float4* __restrict__ c1, float* __restrict__ partials) {
    const int row = blockIdx.x >> 4;   // / SEGS
    const int seg = blockIdx.x & (SEGS - 1);
    const float4* __restrict__ p = c1 + (size_t)row * ROW_VEC + (size_t)seg * SEG_VEC;

    float s = 0.0f;
    for (int i = threadIdx.x; i < SEG_VEC; i += THREADS) {
        float4 v = p[i];
        s += (v.x + v.y) + (v.z + v.w);
    }

    // wave-64 shuffle reduction
    #pragma unroll
    for (int off = 32; off > 0; off >>= 1)
        s += __shfl_down(s, off, 64);

    __shared__ float wsum[THREADS / 64];
    const int lane = threadIdx.x & 63;
    const int wid  = threadIdx.x >> 6;
    if (lane == 0) wsum[wid] = s;
    __syncthreads();
    if (threadIdx.x == 0) {
        float t = 0.0f;
        #pragma unroll
        for (int i = 0; i < THREADS / 64; ++i) t += wsum[i];
        partials[blockIdx.x] = t;
    }
}

// Kernel B: mean = sum(partials[row]) / J; out segment = conv2 segment * mean
__global__ __launch_bounds__(THREADS)
void bp_scale_kernel(const float4* __restrict__ c2,
                     const float* __restrict__ partials,
                     float4* __restrict__ out) {
    const int row = blockIdx.x >> 4;
    const int seg = blockIdx.x & (SEGS - 1);

    float t = 0.0f;
    #pragma unroll
    for (int i = 0; i < SEGS; ++i)
        t += partials[row * SEGS + i];   // wave-uniform -> scalar loads, L2-hot
    const float m = t * (1.0f / (float)ROW_ELEMS);

    const size_t base = (size_t)row * ROW_VEC + (size_t)seg * SEG_VEC;
    const float4* __restrict__ p = c2 + base;
    float4* __restrict__ o = out + base;
    for (int i = threadIdx.x; i < SEG_VEC; i += THREADS) {
        float4 v = p[i];
        v.x *= m; v.y *= m; v.z *= m; v.w *= m;
        o[i] = v;
    }
}

extern "C" void kernel_launch(void* const* d_in, const int* in_sizes, int n_in,
                              void* d_out, int out_size, void* d_ws, size_t ws_size,
                              hipStream_t stream) {
    const float4* c1 = (const float4*)d_in[0];
    const float4* c2 = (const float4*)d_in[1];
    float4* out = (float4*)d_out;
    float* partials = (float*)d_ws;   // NROWS*SEGS floats = 16 KB

    const int grid = NROWS * SEGS;    // 4096 blocks
    bp_reduce_kernel<<<grid, THREADS, 0, stream>>>(c1, partials);
    bp_scale_kernel<<<grid, THREADS, 0, stream>>>(c2, partials, out);
}